// Round 6
// baseline (51.911 us; speedup 1.0000x reference)
//
#include <hip/hip_runtime.h>

typedef __bf16 bf16x8 __attribute__((ext_vector_type(8)));
typedef float f32x16 __attribute__((ext_vector_type(16)));
typedef unsigned u32x2 __attribute__((ext_vector_type(2)));

#define BB 2
#define HH 56
#define WW 56
#define NN 2
#define CC 128
#define NH 8
#define DD 16
#define WSP 7
#define LQ 784           // tokens per window = 56*7*2
#define KB_TOK 800       // K rows per instance (zero-padded 784..799)
#define VT_STRIDE 808    // V^T token stride: 8*101 -> odd 16B-stride, bank-spread
#define NQT 25           // Q tiles of 32
#define NKC 25           // K chunks of 32
#define NINST 128        // 16 windows * 8 heads
#define NWAVE 5          // waves per attn block (1 Q-tile each)
#define BPI 5            // attn blocks per instance
#define SLICE_ELEMS 26112   // bf16 elems per inst slice = 52224 B (16-aligned)
#define SLICE_UINT4 3264    // 52224 / 16
#define VT_OFF 12800        // elem offset of V^T region (800*16)
#define VT_BYTE 25600       // byte offset of V^T region in LDS
#define NB_RPE 3136      // 2*56*56*128 / 256
#define NB_PACK 404      // 128*808 / 256

// scale * log2(e) so P = exp2(S) directly (no max-tracking; S bounded)
#define QSCALE 0.3606737602222409f

union U2 { __bf16 h[2]; unsigned u; };
union U4 { unsigned u[4]; bf16x8 v; };
union H8 { bf16x8 v; uint4 q; };

// ---------------- Kernel 1: fused RPE + K/V pack ---------------------------
// Blocks [0, NB_RPE): depthwise-conv RPE written to out.
// Blocks [NB_RPE, NB_RPE+NB_PACK): pack per-instance contiguous slice:
//   [0..12800)  K  bf16 [tok(800)][16]
//   [12800..25728) V^T bf16 [d(16)][tok stride 808]
__global__ __launch_bounds__(256) void prep_kernel(const float* __restrict__ value,
                                                   const float* __restrict__ conv_w,
                                                   const float* __restrict__ k_g,
                                                   float* __restrict__ out,
                                                   __bf16* __restrict__ ws) {
    const int bx = blockIdx.x;
    const int tid = threadIdx.x;

    if (bx < NB_RPE) {
        int idx = bx * 256 + tid;           // over B*H*W*C (exact)
        int c = idx & (CC - 1);
        int t = idx >> 7;
        int x = t % WW;
        int t2 = t / WW;
        int y = t2 % HH;
        int b = t2 / HH;

        float w[9];
#pragma unroll
        for (int k = 0; k < 9; ++k) w[k] = conv_w[c * 9 + k];

        float conv_sum = 0.f;
#pragma unroll
        for (int dy = -1; dy <= 1; ++dy) {
            int yy = y + dy;
            if (yy < 0 || yy >= HH) continue;
#pragma unroll
            for (int dx = -1; dx <= 1; ++dx) {
                int xx = x + dx;
                if (xx < 0 || xx >= WW) continue;
                const float* p = value + (((long)(b * HH + yy) * WW + xx) * NN) * CC + c;
                float vs = p[0] + p[CC];
                conv_sum += w[(dy + 1) * 3 + (dx + 1)] * vs;
            }
        }
        float center = w[4];
        const float* pc = value + (((long)(b * HH + y) * WW + x) * NN) * CC + c;
        float v0 = pc[0], v1 = pc[CC];
        float base = conv_sum - center * (v0 + v1);
        float* po = out + (((long)(b * HH + y) * WW + x) * NN) * CC + c;
        po[0]  = base + center * v0;
        po[CC] = base + center * v1;
    } else {
        int idx = (bx - NB_RPE) * 256 + tid;   // over NINST*808 (exact)
        int inst = idx / VT_STRIDE;
        int tok  = idx - inst * VT_STRIDE;

        __bf16* kbase = ws + (long)inst * SLICE_ELEMS;
        __bf16* vbase = kbase + VT_OFF;

        if (tok >= LQ) {                        // zero pad
            if (tok < KB_TOK) {
                H8 z; z.q = make_uint4(0, 0, 0, 0);
                uint4* kq = (uint4*)(kbase + tok * 16);
                kq[0] = z.q; kq[1] = z.q;
            }
#pragma unroll
            for (int d = 0; d < 16; ++d)
                vbase[d * VT_STRIDE + tok] = (__bf16)0.f;
            return;
        }

        int head = inst & 7, win = inst >> 3;
        int b = win >> 3, wj = win & 7;
        int pos = tok >> 1, n = tok & 1;
        int y = pos / WSP, xl = pos - y * WSP;
        long off = ((long)(((b * HH + y) * WW + wj * WSP + xl) * NN + n)) * CC + head * DD;

        float kv[16], vv[16];
        *(float4*)&kv[0]  = *(const float4*)(k_g + off);
        *(float4*)&kv[4]  = *(const float4*)(k_g + off + 4);
        *(float4*)&kv[8]  = *(const float4*)(k_g + off + 8);
        *(float4*)&kv[12] = *(const float4*)(k_g + off + 12);
        *(float4*)&vv[0]  = *(const float4*)(value + off);
        *(float4*)&vv[4]  = *(const float4*)(value + off + 4);
        *(float4*)&vv[8]  = *(const float4*)(value + off + 8);
        *(float4*)&vv[12] = *(const float4*)(value + off + 12);

        H8 lo, hi;
#pragma unroll
        for (int i = 0; i < 8; ++i) { lo.v[i] = (__bf16)kv[i]; hi.v[i] = (__bf16)kv[8 + i]; }
        uint4* kq = (uint4*)(kbase + tok * 16);
        kq[0] = lo.q;
        kq[1] = hi.q;

#pragma unroll
        for (int d = 0; d < 16; ++d)
            vbase[d * VT_STRIDE + tok] = (__bf16)vv[d];
    }
}

// ---------------- Kernel 2: MFMA flash attention, LDS-resident K/V ---------
// Grid 640 = 128 inst * 5 parts, XCD-affine (inst&7 == bid&7). Block = 5
// waves; stages the instance's 51KB K/V slice to LDS once, then each wave
// processes one full 32-query tile (qt = part*5 + wave) with no cross-wave
// reduction. Swapped QK^T: S^T = mfma(A=K, B=Q); softmax lane-local, no
// max-tracking. O^T = mfma(A=V^T, B=P).
__global__ __launch_bounds__(320) void attn_mfma(const float* __restrict__ q_g,
                                                 const __bf16* __restrict__ ws,
                                                 float* __restrict__ out) {
    __shared__ uint4 smem4[SLICE_UINT4];   // [K 25600B][V^T 25856B][pad]

    const int bid  = blockIdx.x;
    const int g    = bid >> 3;             // 0..79
    const int inst = (bid & 7) + 8 * (g / BPI);
    const int part = g % BPI;
    const int head = inst & 7;
    const int win  = inst >> 3;

    const int tid  = threadIdx.x;
    const int w    = tid >> 6;             // 0..4
    const int lane = tid & 63;
    const int col  = lane & 31;            // query col / key row / d row
    const int h    = lane >> 5;
    const int dl   = col & 15;

    // ---- stage instance slice global -> LDS (coalesced uint4) ----
    const uint4* src4 = (const uint4*)(ws + (long)inst * SLICE_ELEMS);
    for (int i = tid; i < SLICE_UINT4; i += 320) smem4[i] = src4[i];
    __syncthreads();

    const int qt  = part * NWAVE + w;      // 0..24
    const int myq = qt * 32 + col;
    const int sib = myq ^ 1;

    const int myqc = myq < LQ ? myq : LQ - 1;
    const int b = win >> 3, wj = win & 7;
    const int pos = myqc >> 1, n = myqc & 1;
    const int y = pos / WSP, xl = pos - y * WSP;
    const long ooff = ((long)(((b * HH + y) * WW + wj * WSP + xl) * NN + n)) * CC + head * DD;

    // Q fragment (B operand): col=query, k = d = 8h..8h+7; scale*log2e folded
    bf16x8 qfv;
    {
        const float* qp = q_g + ooff + 8 * h;
        float qv[8];
        *(float4*)&qv[0] = *(const float4*)qp;
        *(float4*)&qv[4] = *(const float4*)(qp + 4);
        H8 qq;
#pragma unroll
        for (int i = 0; i < 8; ++i) qq.v[i] = (__bf16)(qv[i] * QSCALE);
        qfv = qq.v;
    }

    f32x16 acc, zv;
#pragma unroll
    for (int i = 0; i < 16; ++i) { acc[i] = 0.f; zv[i] = 0.f; }
    float lsum = 0.f;

    const char* sb = (const char*)smem4;
    const char* kfp = sb + col * 32 + h * 16;                         // + c*1024
    const char* vfp = sb + VT_BYTE + dl * (VT_STRIDE * 2) + h * 16;   // + c*64 + t*32

    for (int c = 0; c < NKC; ++c) {
        bf16x8 kf = *(const bf16x8*)(kfp + c * 1024);

        f32x16 st = __builtin_amdgcn_mfma_f32_32x32x16_bf16(kf, qfv, zv, 0, 0, 0);

        float p[16];
        if (c == qt || c == NKC - 1) {     // only these chunks need masking
#pragma unroll
            for (int r = 0; r < 16; ++r) {
                int kr = (r & 3) + 8 * (r >> 2) + 4 * h;
                int gk = c * 32 + kr;
                p[r] = (gk >= LQ || gk == sib) ? 0.f : __builtin_amdgcn_exp2f(st[r]);
            }
        } else {
#pragma unroll
            for (int r = 0; r < 16; ++r) p[r] = __builtin_amdgcn_exp2f(st[r]);
        }
        float s0 = (p[0] + p[1]) + (p[2] + p[3]);
        float s1 = (p[4] + p[5]) + (p[6] + p[7]);
        float s2 = (p[8] + p[9]) + (p[10] + p[11]);
        float s3 = (p[12] + p[13]) + (p[14] + p[15]);
        lsum += (s0 + s1) + (s2 + s3);

        // pack P to bf16 pairs; pk[b2] covers keys 8*b2+4h..+3 of this chunk
        unsigned pk[4][2];
#pragma unroll
        for (int b2 = 0; b2 < 4; ++b2) {
            U2 a, bb;
            a.h[0]  = (__bf16)p[4 * b2 + 0];
            a.h[1]  = (__bf16)p[4 * b2 + 1];
            bb.h[0] = (__bf16)p[4 * b2 + 2];
            bb.h[1] = (__bf16)p[4 * b2 + 3];
            pk[b2][0] = a.u;
            pk[b2][1] = bb.u;
        }

#pragma unroll
        for (int t = 0; t < 2; ++t) {
            U4 pb;
#pragma unroll
            for (int j = 0; j < 2; ++j) {
#if __has_builtin(__builtin_amdgcn_permlane32_swap)
                u32x2 rr = __builtin_amdgcn_permlane32_swap(pk[2 * t][j], pk[2 * t + 1][j], false, false);
                pb.u[j]     = rr[0];
                pb.u[2 + j] = rr[1];
#else
                unsigned swa = __shfl_xor(pk[2 * t][j], 32, 64);
                unsigned swb = __shfl_xor(pk[2 * t + 1][j], 32, 64);
                pb.u[j]     = h ? swb : pk[2 * t][j];
                pb.u[2 + j] = h ? pk[2 * t + 1][j] : swa;
#endif
            }
            bf16x8 vf = *(const bf16x8*)(vfp + c * 64 + t * 32);
            acc = __builtin_amdgcn_mfma_f32_32x32x16_bf16(vf, pb.v, acc, 0, 0, 0);
        }
    }

    // combine the two h-halves' lsum; acc needs no cross-lane combine
    float ltot = lsum + __shfl_xor(lsum, 32, 64);

    if (myq < LQ) {
        float inv = 1.f / ltot;
        float* po = out + ooff;
        // regs r=0..3 -> d = 4h+r ; r=4..7 -> d = 8+4h+(r-4)
        float4 r0 = *(float4*)(po + 4 * h);
        r0.x += acc[0] * inv; r0.y += acc[1] * inv;
        r0.z += acc[2] * inv; r0.w += acc[3] * inv;
        *(float4*)(po + 4 * h) = r0;
        float4 r1 = *(float4*)(po + 8 + 4 * h);
        r1.x += acc[4] * inv; r1.y += acc[5] * inv;
        r1.z += acc[6] * inv; r1.w += acc[7] * inv;
        *(float4*)(po + 8 + 4 * h) = r1;
    }
}

extern "C" void kernel_launch(void* const* d_in, const int* in_sizes, int n_in,
                              void* d_out, int out_size, void* d_ws, size_t ws_size,
                              hipStream_t stream) {
    const float* q = (const float*)d_in[0];
    const float* k = (const float*)d_in[1];
    const float* v = (const float*)d_in[2];
    const float* w = (const float*)d_in[3];
    float* out = (float*)d_out;

    __bf16* ws = (__bf16*)d_ws;   // 128 * 26112 bf16 = 6.7 MB

    prep_kernel<<<NB_RPE + NB_PACK, 256, 0, stream>>>(v, w, k, out, ws);

    attn_mfma<<<NINST * BPI, 320, 0, stream>>>(q, ws, out);
}

// Round 8
// 46.823 us; speedup vs baseline: 1.1087x; 1.1087x over previous
//
#include <hip/hip_runtime.h>

typedef __bf16 bf16x8 __attribute__((ext_vector_type(8)));
typedef float f32x16 __attribute__((ext_vector_type(16)));
typedef unsigned u32x2 __attribute__((ext_vector_type(2)));

#define BB 2
#define HH 56
#define WW 56
#define NN 2
#define CC 128
#define NH 8
#define DD 16
#define WSP 7
#define LQ 784           // tokens per window = 56*7*2
#define KB_TOK 800       // K rows per instance (zero-padded 784..799)
#define VT_STRIDE 808    // V^T token stride
#define NQT 25           // Q tiles of 32
#define NKC 25           // K chunks of 32
#define NINST 128        // 16 windows * 8 heads
#define NW 4             // waves per block (K-split factor)
#define VT_OFF 12800     // elem offset of V^T region (800*16)
#define SLICE_ELEMS 26536   // 12800 + 17*808 bf16 elems per instance (6.79 MB total)
#define NB_RPE 3136      // 2*56*56*128 / 256
#define NB_PACK 404      // 128*808 / 256

// scale * log2(e) so P = exp2(S) directly (no max-tracking; S bounded)
#define QSCALE 0.3606737602222409f

union U2 { __bf16 h[2]; unsigned u; };
union U4 { unsigned u[4]; bf16x8 v; };
union H8 { bf16x8 v; uint4 q; };

// ---------------- Kernel 1: fused RPE + K/V pack ---------------------------
// Blocks [0, NB_RPE): depthwise-conv RPE written to out.
// Blocks [NB_RPE, NB_RPE+NB_PACK): per-instance contiguous slice:
//   [0..12800)      K   bf16 [tok(800)][16]
//   [12800..26536)  V^T bf16 [row(17)][tok stride 808]
//     rows 0..15 = V^T data; row 16 = 1.0 (lsum-in-MFMA ones row).
__global__ __launch_bounds__(256) void prep_kernel(const float* __restrict__ value,
                                                   const float* __restrict__ conv_w,
                                                   const float* __restrict__ k_g,
                                                   float* __restrict__ out,
                                                   __bf16* __restrict__ ws) {
    const int bx = blockIdx.x;
    const int tid = threadIdx.x;

    if (bx < NB_RPE) {
        int idx = bx * 256 + tid;           // over B*H*W*C (exact)
        int c = idx & (CC - 1);
        int t = idx >> 7;
        int x = t % WW;
        int t2 = t / WW;
        int y = t2 % HH;
        int b = t2 / HH;

        float w[9];
#pragma unroll
        for (int k = 0; k < 9; ++k) w[k] = conv_w[c * 9 + k];

        float conv_sum = 0.f;
#pragma unroll
        for (int dy = -1; dy <= 1; ++dy) {
            int yy = y + dy;
            if (yy < 0 || yy >= HH) continue;
#pragma unroll
            for (int dx = -1; dx <= 1; ++dx) {
                int xx = x + dx;
                if (xx < 0 || xx >= WW) continue;
                const float* p = value + (((long)(b * HH + yy) * WW + xx) * NN) * CC + c;
                float vs = p[0] + p[CC];
                conv_sum += w[(dy + 1) * 3 + (dx + 1)] * vs;
            }
        }
        float center = w[4];
        const float* pc = value + (((long)(b * HH + y) * WW + x) * NN) * CC + c;
        float v0 = pc[0], v1 = pc[CC];
        float base = conv_sum - center * (v0 + v1);
        float* po = out + (((long)(b * HH + y) * WW + x) * NN) * CC + c;
        po[0]  = base + center * v0;
        po[CC] = base + center * v1;
    } else {
        int idx = (bx - NB_RPE) * 256 + tid;   // over NINST*808 (exact)
        int inst = idx / VT_STRIDE;
        int tok  = idx - inst * VT_STRIDE;

        __bf16* kbase = ws + (long)inst * SLICE_ELEMS;
        __bf16* vbase = kbase + VT_OFF;

        // ones row 16 (lsum-in-MFMA)
        vbase[16 * VT_STRIDE + tok] = (__bf16)1.f;

        if (tok >= LQ) {                        // zero pad
            if (tok < KB_TOK) {
                H8 z; z.q = make_uint4(0, 0, 0, 0);
                uint4* kq = (uint4*)(kbase + tok * 16);
                kq[0] = z.q; kq[1] = z.q;
            }
#pragma unroll
            for (int d = 0; d < 16; ++d)
                vbase[d * VT_STRIDE + tok] = (__bf16)0.f;
            return;
        }

        int head = inst & 7, win = inst >> 3;
        int b = win >> 3, wj = win & 7;
        int pos = tok >> 1, n = tok & 1;
        int y = pos / WSP, xl = pos - y * WSP;
        long off = ((long)(((b * HH + y) * WW + wj * WSP + xl) * NN + n)) * CC + head * DD;

        float kv[16], vv[16];
        *(float4*)&kv[0]  = *(const float4*)(k_g + off);
        *(float4*)&kv[4]  = *(const float4*)(k_g + off + 4);
        *(float4*)&kv[8]  = *(const float4*)(k_g + off + 8);
        *(float4*)&kv[12] = *(const float4*)(k_g + off + 12);
        *(float4*)&vv[0]  = *(const float4*)(value + off);
        *(float4*)&vv[4]  = *(const float4*)(value + off + 4);
        *(float4*)&vv[8]  = *(const float4*)(value + off + 8);
        *(float4*)&vv[12] = *(const float4*)(value + off + 12);

        H8 lo, hi;
#pragma unroll
        for (int i = 0; i < 8; ++i) { lo.v[i] = (__bf16)kv[i]; hi.v[i] = (__bf16)kv[8 + i]; }
        uint4* kq = (uint4*)(kbase + tok * 16);
        kq[0] = lo.q;
        kq[1] = hi.q;

#pragma unroll
        for (int d = 0; d < 16; ++d)
            vbase[d * VT_STRIDE + tok] = (__bf16)vv[d];
    }
}

// ---------------- Kernel 2: MFMA flash attention, 4-wave K-split -----------
// L2-direct (instance slice is L2-resident via XCD-affine swizzle).
// Swapped QK^T: S^T = mfma(A=K, B=Q) -> lane owns query col; softmax
// lane-local, no max-tracking. O^T = mfma(A=V^T, B=P); lanes with col>=16
// load the ones row (16), so D rows 16..31 all equal lsum -> acc[8] is the
// softmax denominator for both h halves, free.
__global__ __launch_bounds__(256) void attn_mfma(const float* __restrict__ q_g,
                                                 const __bf16* __restrict__ ws,
                                                 float* __restrict__ out) {
    __shared__ float red[NW][64][11];   // per-wave partials: 8 d + lsum

    const int bid  = blockIdx.x;
    const int slot = bid >> 3;              // 0..399
    const int inst = (bid & 7) + 8 * (slot / 25);
    const int qt   = slot % 25;
    const int head = inst & 7;
    const int win  = inst >> 3;

    const int tid  = threadIdx.x;
    const int w    = tid >> 6;
    const int lane = tid & 63;
    const int col  = lane & 31;        // query col / key row / V^T row
    const int h    = lane >> 5;
    const int q0   = qt * 32;
    const int myq  = q0 + col;
    const int sib  = myq ^ 1;

    const int myqc = myq < LQ ? myq : LQ - 1;
    const int b = win >> 3, wj = win & 7;
    const int pos = myqc >> 1, n = myqc & 1;
    const int y = pos / WSP, xl = pos - y * WSP;
    const long ooff = ((long)(((b * HH + y) * WW + wj * WSP + xl) * NN + n)) * CC + head * DD;

    // Q fragment (B operand): col=query, k = d = 8h..8h+7; scale*log2e folded
    bf16x8 qfv;
    {
        const float* qp = q_g + ooff + 8 * h;
        float qv[8];
        *(float4*)&qv[0] = *(const float4*)qp;
        *(float4*)&qv[4] = *(const float4*)(qp + 4);
        H8 qq;
#pragma unroll
        for (int i = 0; i < 8; ++i) qq.v[i] = (__bf16)(qv[i] * QSCALE);
        qfv = qq.v;
    }

    f32x16 acc, zv;
#pragma unroll
    for (int i = 0; i < 16; ++i) { acc[i] = 0.f; zv[i] = 0.f; }

    const __bf16* base = ws + (long)inst * SLICE_ELEMS;
    const bf16x8* kpb = (const bf16x8*)base + col * 2 + h;            // + c*64
    const int vrow = col < 16 ? col : 16;                             // clamp to ones row
    const __bf16* vp = base + VT_OFF + vrow * VT_STRIDE + 8 * h;      // + c*32 + 16t

    for (int c = w; c < NKC; c += NW) {
        bf16x8 kf = kpb[(long)c * 64];

        f32x16 st = __builtin_amdgcn_mfma_f32_32x32x16_bf16(kf, qfv, zv, 0, 0, 0);

        float p[16];
        if (c == qt || c == NKC - 1) {  // only these chunks need masking
#pragma unroll
            for (int r = 0; r < 16; ++r) {
                int kr = (r & 3) + 8 * (r >> 2) + 4 * h;
                int gk = c * 32 + kr;
                p[r] = (gk >= LQ || gk == sib) ? 0.f : __builtin_amdgcn_exp2f(st[r]);
            }
        } else {
#pragma unroll
            for (int r = 0; r < 16; ++r) p[r] = __builtin_amdgcn_exp2f(st[r]);
        }

        // pack P to bf16 pairs; pk[b2] covers keys 8*b2+4h..+3 of this chunk
        unsigned pk[4][2];
#pragma unroll
        for (int b2 = 0; b2 < 4; ++b2) {
            U2 a, bb;
            a.h[0]  = (__bf16)p[4 * b2 + 0];
            a.h[1]  = (__bf16)p[4 * b2 + 1];
            bb.h[0] = (__bf16)p[4 * b2 + 2];
            bb.h[1] = (__bf16)p[4 * b2 + 3];
            pk[b2][0] = a.u;
            pk[b2][1] = bb.u;
        }

#pragma unroll
        for (int t = 0; t < 2; ++t) {
            U4 pb;
#pragma unroll
            for (int j = 0; j < 2; ++j) {
#if __has_builtin(__builtin_amdgcn_permlane32_swap)
                u32x2 rr = __builtin_amdgcn_permlane32_swap(pk[2 * t][j], pk[2 * t + 1][j], false, false);
                pb.u[j]     = rr[0];
                pb.u[2 + j] = rr[1];
#else
                unsigned swa = __shfl_xor(pk[2 * t][j], 32, 64);
                unsigned swb = __shfl_xor(pk[2 * t + 1][j], 32, 64);
                pb.u[j]     = h ? swb : pk[2 * t][j];
                pb.u[2 + j] = h ? pk[2 * t + 1][j] : swa;
#endif
            }
            bf16x8 vf = *(const bf16x8*)(vp + c * 32 + 16 * t);
            acc = __builtin_amdgcn_mfma_f32_32x32x16_bf16(vf, pb.v, acc, 0, 0, 0);
        }
    }

    // per-wave partials: regs 0..7 = d rows, reg 8 = lsum (ones row)
#pragma unroll
    for (int i = 0; i < 9; ++i) red[w][lane][i] = acc[i];
    __syncthreads();

    if (w == 0 && myq < LQ) {
        float o[9];
#pragma unroll
        for (int i = 0; i < 9; ++i)
            o[i] = (red[0][lane][i] + red[1][lane][i]) + (red[2][lane][i] + red[3][lane][i]);
        float inv = 1.f / o[8];
        float* po = out + ooff;
        // regs r=0..3 -> d = 4h+r ; r=4..7 -> d = 8+4h+(r-4)
        float4 r0 = *(float4*)(po + 4 * h);
        r0.x += o[0] * inv; r0.y += o[1] * inv;
        r0.z += o[2] * inv; r0.w += o[3] * inv;
        *(float4*)(po + 4 * h) = r0;
        float4 r1 = *(float4*)(po + 8 + 4 * h);
        r1.x += o[4] * inv; r1.y += o[5] * inv;
        r1.z += o[6] * inv; r1.w += o[7] * inv;
        *(float4*)(po + 8 + 4 * h) = r1;
    }
}

extern "C" void kernel_launch(void* const* d_in, const int* in_sizes, int n_in,
                              void* d_out, int out_size, void* d_ws, size_t ws_size,
                              hipStream_t stream) {
    const float* q = (const float*)d_in[0];
    const float* k = (const float*)d_in[1];
    const float* v = (const float*)d_in[2];
    const float* w = (const float*)d_in[3];
    float* out = (float*)d_out;

    __bf16* ws = (__bf16*)d_ws;   // 128 * 26536 bf16 = 6.79 MB

    prep_kernel<<<NB_RPE + NB_PACK, 256, 0, stream>>>(v, w, k, out, ws);

    attn_mfma<<<NQT * NH * 16, 256, 0, stream>>>(q, ws, out);
}

// Round 9
// 44.892 us; speedup vs baseline: 1.1564x; 1.0430x over previous
//
#include <hip/hip_runtime.h>

typedef __bf16 bf16x8 __attribute__((ext_vector_type(8)));
typedef float f32x16 __attribute__((ext_vector_type(16)));
typedef unsigned u32x2 __attribute__((ext_vector_type(2)));

#define BB 2
#define HH 56
#define WW 56
#define NN 2
#define CC 128
#define NH 8
#define DD 16
#define WSP 7
#define LQ 784           // tokens per window = 56*7*2
#define KB_TOK 800       // K rows per instance (zero-padded 784..799)
#define VT_STRIDE 808    // V^T token stride
#define NQT 25           // Q tiles of 32
#define NKC 25           // K chunks of 32
#define NINST 128        // 16 windows * 8 heads
#define NW 4             // waves per block (K-split factor)
#define VT_OFF 12800     // elem offset of V^T region (800*16)
#define SLICE_ELEMS 26536   // 12800 + 17*808 bf16 elems per instance (6.79 MB total)
#define YSTRIP 7         // y rows per RPE thread
#define NB_RPE 448       // B * 8 strips * 28 blocks (256 thr over 56x*128c)
#define NB_PACK 404      // 128*808 / 256
#define YSTRD 14336      // y stride in elements = 56*2*128
#define BSTRD 802816     // b stride = 56*56*2*128

// scale * log2(e) so P = exp2(S) directly (no max-tracking; S bounded)
#define QSCALE 0.3606737602222409f

union U2 { __bf16 h[2]; unsigned u; };
union U4 { unsigned u[4]; bf16x8 v; };
union H8 { bf16x8 v; uint4 q; };

// ---------------- Kernel 1: fused RPE (y-sliding) + K/V pack ---------------
// Blocks [0, NB_RPE): RPE. Thread owns (b,x,c), slides a 3x3 n-summed-S
// window down 7 rows of y; 7 coalesced loads per output pair (vs 40).
// Blocks [NB_RPE, NB_RPE+NB_PACK): per-instance packed slice:
//   [0..12800)      K   bf16 [tok(800)][16]
//   [12800..26536)  V^T bf16 [row(17)][tok stride 808]; row 16 = ones (lsum).
__global__ __launch_bounds__(256) void prep_kernel(const float* __restrict__ value,
                                                   const float* __restrict__ conv_w,
                                                   const float* __restrict__ k_g,
                                                   float* __restrict__ out,
                                                   __bf16* __restrict__ ws) {
    const int bx = blockIdx.x;
    const int tid = threadIdx.x;

    if (bx < NB_RPE) {
        // decompose: b (2) x strip (8) x blk (28)
        const int b     = bx / 224;
        const int r0    = bx - b * 224;
        const int strip = r0 / 28;
        const int blk   = r0 - strip * 28;
        const int idx   = blk * 256 + tid;      // over 56x * 128c
        const int c     = idx & 127;
        const int x     = idx >> 7;             // 0..55
        const int y0    = strip * YSTRIP;

        float w[9];
#pragma unroll
        for (int k = 0; k < 9; ++k) w[k] = conv_w[c * 9 + k];
        const float center = w[4];

        const float* vb = value + (long)b * BSTRD + x * (NN * CC) + c;
        float* ob = out + (long)b * BSTRD + x * (NN * CC) + c;
        const bool xm = x > 0, xp = x < WW - 1;

        // n-summed S at (y, x+dx)
        auto loadS = [&](int y, int dx) -> float {
            const float* p = vb + y * YSTRD + dx * (NN * CC);
            return p[0] + p[CC];
        };

        float sm[3], s0[3], sp[3];
        if (y0 > 0) {
            sm[0] = xm ? loadS(y0 - 1, -1) : 0.f;
            sm[1] = loadS(y0 - 1, 0);
            sm[2] = xp ? loadS(y0 - 1, 1) : 0.f;
        } else { sm[0] = sm[1] = sm[2] = 0.f; }
        s0[0] = xm ? loadS(y0, -1) : 0.f;
        s0[1] = loadS(y0, 0);
        s0[2] = xp ? loadS(y0, 1) : 0.f;

#pragma unroll
        for (int yy = 0; yy < YSTRIP; ++yy) {
            const int y = y0 + yy;
            if (y + 1 < HH) {
                sp[0] = xm ? loadS(y + 1, -1) : 0.f;
                sp[1] = loadS(y + 1, 0);
                sp[2] = xp ? loadS(y + 1, 1) : 0.f;
            } else { sp[0] = sp[1] = sp[2] = 0.f; }

            float conv_sum = w[0] * sm[0] + w[1] * sm[1] + w[2] * sm[2]
                           + w[3] * s0[0] + w[4] * s0[1] + w[5] * s0[2]
                           + w[6] * sp[0] + w[7] * sp[1] + w[8] * sp[2];
            float v0 = vb[y * YSTRD];          // n=0 center
            float v1 = s0[1] - v0;
            float base = conv_sum - center * s0[1];
            float* po = ob + y * YSTRD;
            po[0]  = base + center * v0;
            po[CC] = base + center * v1;

            sm[0] = s0[0]; sm[1] = s0[1]; sm[2] = s0[2];
            s0[0] = sp[0]; s0[1] = sp[1]; s0[2] = sp[2];
        }
    } else {
        int idx = (bx - NB_RPE) * 256 + tid;   // over NINST*808 (exact)
        int inst = idx / VT_STRIDE;
        int tok  = idx - inst * VT_STRIDE;

        __bf16* kbase = ws + (long)inst * SLICE_ELEMS;
        __bf16* vbase = kbase + VT_OFF;

        // ones row 16 (lsum-in-MFMA)
        vbase[16 * VT_STRIDE + tok] = (__bf16)1.f;

        if (tok >= LQ) {                        // zero pad
            if (tok < KB_TOK) {
                H8 z; z.q = make_uint4(0, 0, 0, 0);
                uint4* kq = (uint4*)(kbase + tok * 16);
                kq[0] = z.q; kq[1] = z.q;
            }
#pragma unroll
            for (int d = 0; d < 16; ++d)
                vbase[d * VT_STRIDE + tok] = (__bf16)0.f;
            return;
        }

        int head = inst & 7, win = inst >> 3;
        int b = win >> 3, wj = win & 7;
        int pos = tok >> 1, n = tok & 1;
        int y = pos / WSP, xl = pos - y * WSP;
        long off = ((long)(((b * HH + y) * WW + wj * WSP + xl) * NN + n)) * CC + head * DD;

        float kv[16], vv[16];
        *(float4*)&kv[0]  = *(const float4*)(k_g + off);
        *(float4*)&kv[4]  = *(const float4*)(k_g + off + 4);
        *(float4*)&kv[8]  = *(const float4*)(k_g + off + 8);
        *(float4*)&kv[12] = *(const float4*)(k_g + off + 12);
        *(float4*)&vv[0]  = *(const float4*)(value + off);
        *(float4*)&vv[4]  = *(const float4*)(value + off + 4);
        *(float4*)&vv[8]  = *(const float4*)(value + off + 8);
        *(float4*)&vv[12] = *(const float4*)(value + off + 12);

        H8 lo, hi;
#pragma unroll
        for (int i = 0; i < 8; ++i) { lo.v[i] = (__bf16)kv[i]; hi.v[i] = (__bf16)kv[8 + i]; }
        uint4* kq = (uint4*)(kbase + tok * 16);
        kq[0] = lo.q;
        kq[1] = hi.q;

#pragma unroll
        for (int d = 0; d < 16; ++d)
            vbase[d * VT_STRIDE + tok] = (__bf16)vv[d];
    }
}

// ---------------- Kernel 2: MFMA flash attention, 4-wave K-split -----------
// (unchanged from R8) L2-direct; swapped QK^T; no max-tracking; ones-row
// lsum via acc[8].
__global__ __launch_bounds__(256) void attn_mfma(const float* __restrict__ q_g,
                                                 const __bf16* __restrict__ ws,
                                                 float* __restrict__ out) {
    __shared__ float red[NW][64][11];   // per-wave partials: 8 d + lsum

    const int bid  = blockIdx.x;
    const int slot = bid >> 3;              // 0..399
    const int inst = (bid & 7) + 8 * (slot / 25);
    const int qt   = slot % 25;
    const int head = inst & 7;
    const int win  = inst >> 3;

    const int tid  = threadIdx.x;
    const int w    = tid >> 6;
    const int lane = tid & 63;
    const int col  = lane & 31;        // query col / key row / V^T row
    const int h    = lane >> 5;
    const int q0   = qt * 32;
    const int myq  = q0 + col;
    const int sib  = myq ^ 1;

    const int myqc = myq < LQ ? myq : LQ - 1;
    const int b = win >> 3, wj = win & 7;
    const int pos = myqc >> 1, n = myqc & 1;
    const int y = pos / WSP, xl = pos - y * WSP;
    const long ooff = ((long)(((b * HH + y) * WW + wj * WSP + xl) * NN + n)) * CC + head * DD;

    // Q fragment (B operand): col=query, k = d = 8h..8h+7; scale*log2e folded
    bf16x8 qfv;
    {
        const float* qp = q_g + ooff + 8 * h;
        float qv[8];
        *(float4*)&qv[0] = *(const float4*)qp;
        *(float4*)&qv[4] = *(const float4*)(qp + 4);
        H8 qq;
#pragma unroll
        for (int i = 0; i < 8; ++i) qq.v[i] = (__bf16)(qv[i] * QSCALE);
        qfv = qq.v;
    }

    f32x16 acc, zv;
#pragma unroll
    for (int i = 0; i < 16; ++i) { acc[i] = 0.f; zv[i] = 0.f; }

    const __bf16* base = ws + (long)inst * SLICE_ELEMS;
    const bf16x8* kpb = (const bf16x8*)base + col * 2 + h;            // + c*64
    const int vrow = col < 16 ? col : 16;                             // clamp to ones row
    const __bf16* vp = base + VT_OFF + vrow * VT_STRIDE + 8 * h;      // + c*32 + 16t

    for (int c = w; c < NKC; c += NW) {
        bf16x8 kf = kpb[(long)c * 64];

        f32x16 st = __builtin_amdgcn_mfma_f32_32x32x16_bf16(kf, qfv, zv, 0, 0, 0);

        float p[16];
        if (c == qt || c == NKC - 1) {  // only these chunks need masking
#pragma unroll
            for (int r = 0; r < 16; ++r) {
                int kr = (r & 3) + 8 * (r >> 2) + 4 * h;
                int gk = c * 32 + kr;
                p[r] = (gk >= LQ || gk == sib) ? 0.f : __builtin_amdgcn_exp2f(st[r]);
            }
        } else {
#pragma unroll
            for (int r = 0; r < 16; ++r) p[r] = __builtin_amdgcn_exp2f(st[r]);
        }

        // pack P to bf16 pairs; pk[b2] covers keys 8*b2+4h..+3 of this chunk
        unsigned pk[4][2];
#pragma unroll
        for (int b2 = 0; b2 < 4; ++b2) {
            U2 a, bb;
            a.h[0]  = (__bf16)p[4 * b2 + 0];
            a.h[1]  = (__bf16)p[4 * b2 + 1];
            bb.h[0] = (__bf16)p[4 * b2 + 2];
            bb.h[1] = (__bf16)p[4 * b2 + 3];
            pk[b2][0] = a.u;
            pk[b2][1] = bb.u;
        }

#pragma unroll
        for (int t = 0; t < 2; ++t) {
            U4 pb;
#pragma unroll
            for (int j = 0; j < 2; ++j) {
#if __has_builtin(__builtin_amdgcn_permlane32_swap)
                u32x2 rr = __builtin_amdgcn_permlane32_swap(pk[2 * t][j], pk[2 * t + 1][j], false, false);
                pb.u[j]     = rr[0];
                pb.u[2 + j] = rr[1];
#else
                unsigned swa = __shfl_xor(pk[2 * t][j], 32, 64);
                unsigned swb = __shfl_xor(pk[2 * t + 1][j], 32, 64);
                pb.u[j]     = h ? swb : pk[2 * t][j];
                pb.u[2 + j] = h ? pk[2 * t + 1][j] : swa;
#endif
            }
            bf16x8 vf = *(const bf16x8*)(vp + c * 32 + 16 * t);
            acc = __builtin_amdgcn_mfma_f32_32x32x16_bf16(vf, pb.v, acc, 0, 0, 0);
        }
    }

    // per-wave partials: regs 0..7 = d rows, reg 8 = lsum (ones row)
#pragma unroll
    for (int i = 0; i < 9; ++i) red[w][lane][i] = acc[i];
    __syncthreads();

    if (w == 0 && myq < LQ) {
        float o[9];
#pragma unroll
        for (int i = 0; i < 9; ++i)
            o[i] = (red[0][lane][i] + red[1][lane][i]) + (red[2][lane][i] + red[3][lane][i]);
        float inv = 1.f / o[8];
        float* po = out + ooff;
        // regs r=0..3 -> d = 4h+r ; r=4..7 -> d = 8+4h+(r-4)
        float4 r0 = *(float4*)(po + 4 * h);
        r0.x += o[0] * inv; r0.y += o[1] * inv;
        r0.z += o[2] * inv; r0.w += o[3] * inv;
        *(float4*)(po + 4 * h) = r0;
        float4 r1 = *(float4*)(po + 8 + 4 * h);
        r1.x += o[4] * inv; r1.y += o[5] * inv;
        r1.z += o[6] * inv; r1.w += o[7] * inv;
        *(float4*)(po + 8 + 4 * h) = r1;
    }
}

extern "C" void kernel_launch(void* const* d_in, const int* in_sizes, int n_in,
                              void* d_out, int out_size, void* d_ws, size_t ws_size,
                              hipStream_t stream) {
    const float* q = (const float*)d_in[0];
    const float* k = (const float*)d_in[1];
    const float* v = (const float*)d_in[2];
    const float* w = (const float*)d_in[3];
    float* out = (float*)d_out;

    __bf16* ws = (__bf16*)d_ws;   // 128 * 26536 bf16 = 6.79 MB

    prep_kernel<<<NB_RPE + NB_PACK, 256, 0, stream>>>(v, w, k, out, ws);

    attn_mfma<<<NQT * NH * 16, 256, 0, stream>>>(q, ws, out);
}

// Round 10
// 44.808 us; speedup vs baseline: 1.1585x; 1.0019x over previous
//
#include <hip/hip_runtime.h>

typedef __bf16 bf16x8 __attribute__((ext_vector_type(8)));
typedef float f32x16 __attribute__((ext_vector_type(16)));
typedef unsigned u32x2 __attribute__((ext_vector_type(2)));

#define BB 2
#define HH 56
#define WW 56
#define NN 2
#define CC 128
#define NH 8
#define DD 16
#define WSP 7
#define LQ 784           // tokens per window = 56*7*2
#define KB_TOK 800       // K rows (zero-padded 784..799)
#define VT_STRIDE 808    // V^T token stride (bf16 elems)
#define NKC 25           // K chunks of 32
#define NINST 128        // 16 windows * 8 heads
#define BPI 5            // attn blocks per instance
#define NWAVE 5          // waves per attn block (1 Q-tile each)
#define YSTRIP 7         // y rows per RPE thread
#define NB_RPE 448       // B * 8 strips * 28 blocks
#define YSTRD 14336      // y stride in elements = 56*2*128
#define BSTRD 802816     // b stride = 56*56*2*128

// scale * log2(e) so P = exp2(S) directly (no max-tracking; S bounded)
#define QSCALE 0.3606737602222409f

union U2 { __bf16 h[2]; unsigned u; };
union U4 { unsigned u[4]; bf16x8 v; };
union H8 { bf16x8 v; uint4 q; };

// ---------------- Kernel 1: RPE (y-sliding depthwise conv) -----------------
__global__ __launch_bounds__(256) void rpe_kernel(const float* __restrict__ value,
                                                  const float* __restrict__ conv_w,
                                                  float* __restrict__ out) {
    const int bx = blockIdx.x;
    const int tid = threadIdx.x;
    // decompose: b (2) x strip (8) x blk (28)
    const int b     = bx / 224;
    const int r0    = bx - b * 224;
    const int strip = r0 / 28;
    const int blk   = r0 - strip * 28;
    const int idx   = blk * 256 + tid;      // over 56x * 128c
    const int c     = idx & 127;
    const int x     = idx >> 7;             // 0..55
    const int y0    = strip * YSTRIP;

    float w[9];
#pragma unroll
    for (int k = 0; k < 9; ++k) w[k] = conv_w[c * 9 + k];
    const float center = w[4];

    const float* vb = value + (long)b * BSTRD + x * (NN * CC) + c;
    float* ob = out + (long)b * BSTRD + x * (NN * CC) + c;
    const bool xm = x > 0, xp = x < WW - 1;

    auto loadS = [&](int y, int dx) -> float {
        const float* p = vb + y * YSTRD + dx * (NN * CC);
        return p[0] + p[CC];
    };

    float sm[3], s0[3], sp[3];
    if (y0 > 0) {
        sm[0] = xm ? loadS(y0 - 1, -1) : 0.f;
        sm[1] = loadS(y0 - 1, 0);
        sm[2] = xp ? loadS(y0 - 1, 1) : 0.f;
    } else { sm[0] = sm[1] = sm[2] = 0.f; }
    s0[0] = xm ? loadS(y0, -1) : 0.f;
    s0[1] = loadS(y0, 0);
    s0[2] = xp ? loadS(y0, 1) : 0.f;

#pragma unroll
    for (int yy = 0; yy < YSTRIP; ++yy) {
        const int y = y0 + yy;
        if (y + 1 < HH) {
            sp[0] = xm ? loadS(y + 1, -1) : 0.f;
            sp[1] = loadS(y + 1, 0);
            sp[2] = xp ? loadS(y + 1, 1) : 0.f;
        } else { sp[0] = sp[1] = sp[2] = 0.f; }

        float conv_sum = w[0] * sm[0] + w[1] * sm[1] + w[2] * sm[2]
                       + w[3] * s0[0] + w[4] * s0[1] + w[5] * s0[2]
                       + w[6] * sp[0] + w[7] * sp[1] + w[8] * sp[2];
        float v0 = vb[y * YSTRD];          // n=0 center
        float v1 = s0[1] - v0;
        float base = conv_sum - center * s0[1];
        float* po = ob + y * YSTRD;
        po[0]  = base + center * v0;
        po[CC] = base + center * v1;

        sm[0] = s0[0]; sm[1] = s0[1]; sm[2] = s0[2];
        s0[0] = sp[0]; s0[1] = sp[1]; s0[2] = sp[2];
    }
}

// ---------------- Kernel 2: fused pack+attention, LDS-resident K/V --------
// Grid 640 = 128 inst * 5 parts, XCD-affine (same-inst blocks share an XCD's
// L2 for the f32 source reads). Block = 320 threads: packs its instance's
// K (bf16 [800][16]) and V^T (bf16 [17][808], row 16 = ones for lsum) from
// the f32 sources straight into LDS, then each of the 5 waves runs one full
// 32-query tile: swapped QK^T (S^T = mfma(K,Q), softmax lane-local, no
// max-tracking), O^T = mfma(V^T, P) with acc[8] = denominator. No K-split,
// no cross-wave reduction, no workspace.
__global__ __launch_bounds__(320) void attn_fused(const float* __restrict__ q_g,
                                                  const float* __restrict__ k_g,
                                                  const float* __restrict__ v_g,
                                                  float* __restrict__ out) {
    __shared__ alignas(16) __bf16 Klds[KB_TOK * 16];       // 25600 B
    __shared__ alignas(16) __bf16 Vlds[17 * VT_STRIDE];    // 27472 B

    const int bid  = blockIdx.x;
    const int g    = bid >> 3;             // 0..79
    const int inst = (bid & 7) + 8 * (g / BPI);
    const int part = g % BPI;
    const int head = inst & 7;
    const int win  = inst >> 3;
    const int b    = win >> 3, wj = win & 7;

    const int tid  = threadIdx.x;

    // ---- pack phase: f32 sources -> bf16 LDS (fragment layout) ----
    for (int tok = tid; tok < KB_TOK; tok += 320) {
        Vlds[16 * VT_STRIDE + tok] = (__bf16)1.f;          // ones row (lsum)
        if (tok < LQ) {
            int pos = tok >> 1, n = tok & 1;
            int y = pos / WSP, xl = pos - y * WSP;
            long off = ((long)(((b * HH + y) * WW + wj * WSP + xl) * NN + n)) * CC + head * DD;

            float kv[16], vv[16];
            *(float4*)&kv[0]  = *(const float4*)(k_g + off);
            *(float4*)&kv[4]  = *(const float4*)(k_g + off + 4);
            *(float4*)&kv[8]  = *(const float4*)(k_g + off + 8);
            *(float4*)&kv[12] = *(const float4*)(k_g + off + 12);
            *(float4*)&vv[0]  = *(const float4*)(v_g + off);
            *(float4*)&vv[4]  = *(const float4*)(v_g + off + 4);
            *(float4*)&vv[8]  = *(const float4*)(v_g + off + 8);
            *(float4*)&vv[12] = *(const float4*)(v_g + off + 12);

            H8 lo, hi;
#pragma unroll
            for (int i = 0; i < 8; ++i) { lo.v[i] = (__bf16)kv[i]; hi.v[i] = (__bf16)kv[8 + i]; }
            *(uint4*)&Klds[tok * 16]     = lo.q;
            *(uint4*)&Klds[tok * 16 + 8] = hi.q;
#pragma unroll
            for (int d = 0; d < 16; ++d)
                Vlds[d * VT_STRIDE + tok] = (__bf16)vv[d];
        } else {
            H8 z; z.q = make_uint4(0, 0, 0, 0);
            *(uint4*)&Klds[tok * 16]     = z.q;
            *(uint4*)&Klds[tok * 16 + 8] = z.q;
#pragma unroll
            for (int d = 0; d < 16; ++d)
                Vlds[d * VT_STRIDE + tok] = (__bf16)0.f;
        }
    }
    __syncthreads();

    // ---- attention phase: one full Q-tile per wave ----
    const int w    = tid >> 6;             // 0..4
    const int lane = tid & 63;
    const int col  = lane & 31;            // query col / key row / V^T row
    const int h    = lane >> 5;
    const int qt   = part * NWAVE + w;     // 0..24
    const int myq  = qt * 32 + col;
    const int sib  = myq ^ 1;

    const int myqc = myq < LQ ? myq : LQ - 1;
    const int pos = myqc >> 1, n = myqc & 1;
    const int y = pos / WSP, xl = pos - y * WSP;
    const long ooff = ((long)(((b * HH + y) * WW + wj * WSP + xl) * NN + n)) * CC + head * DD;

    // Q fragment (B operand): col=query, k = d = 8h..8h+7; scale*log2e folded
    bf16x8 qfv;
    {
        const float* qp = q_g + ooff + 8 * h;
        float qv[8];
        *(float4*)&qv[0] = *(const float4*)qp;
        *(float4*)&qv[4] = *(const float4*)(qp + 4);
        H8 qq;
#pragma unroll
        for (int i = 0; i < 8; ++i) qq.v[i] = (__bf16)(qv[i] * QSCALE);
        qfv = qq.v;
    }

    f32x16 acc, zv;
#pragma unroll
    for (int i = 0; i < 16; ++i) { acc[i] = 0.f; zv[i] = 0.f; }

    const char* kbase = (const char*)Klds + col * 32 + h * 16;              // + c*1024
    const int vrow = col < 16 ? col : 16;                                   // clamp to ones row
    const char* vbase = (const char*)Vlds + vrow * (VT_STRIDE * 2) + h * 16; // + c*64 + t*32

    for (int c = 0; c < NKC; ++c) {
        bf16x8 kf = *(const bf16x8*)(kbase + c * 1024);

        f32x16 st = __builtin_amdgcn_mfma_f32_32x32x16_bf16(kf, qfv, zv, 0, 0, 0);

        float p[16];
        if (c == qt || c == NKC - 1) {  // only these chunks need masking
#pragma unroll
            for (int r = 0; r < 16; ++r) {
                int kr = (r & 3) + 8 * (r >> 2) + 4 * h;
                int gk = c * 32 + kr;
                p[r] = (gk >= LQ || gk == sib) ? 0.f : __builtin_amdgcn_exp2f(st[r]);
            }
        } else {
#pragma unroll
            for (int r = 0; r < 16; ++r) p[r] = __builtin_amdgcn_exp2f(st[r]);
        }

        // pack P to bf16 pairs; pk[b2] covers keys 8*b2+4h..+3 of this chunk
        unsigned pk[4][2];
#pragma unroll
        for (int b2 = 0; b2 < 4; ++b2) {
            U2 a, bb;
            a.h[0]  = (__bf16)p[4 * b2 + 0];
            a.h[1]  = (__bf16)p[4 * b2 + 1];
            bb.h[0] = (__bf16)p[4 * b2 + 2];
            bb.h[1] = (__bf16)p[4 * b2 + 3];
            pk[b2][0] = a.u;
            pk[b2][1] = bb.u;
        }

#pragma unroll
        for (int t = 0; t < 2; ++t) {
            U4 pb;
#pragma unroll
            for (int j = 0; j < 2; ++j) {
#if __has_builtin(__builtin_amdgcn_permlane32_swap)
                u32x2 rr = __builtin_amdgcn_permlane32_swap(pk[2 * t][j], pk[2 * t + 1][j], false, false);
                pb.u[j]     = rr[0];
                pb.u[2 + j] = rr[1];
#else
                unsigned swa = __shfl_xor(pk[2 * t][j], 32, 64);
                unsigned swb = __shfl_xor(pk[2 * t + 1][j], 32, 64);
                pb.u[j]     = h ? swb : pk[2 * t][j];
                pb.u[2 + j] = h ? pk[2 * t + 1][j] : swa;
#endif
            }
            bf16x8 vf = *(const bf16x8*)(vbase + c * 64 + t * 32);
            acc = __builtin_amdgcn_mfma_f32_32x32x16_bf16(vf, pb.v, acc, 0, 0, 0);
        }
    }

    // epilogue: acc[8] = lsum (ones row); regs 0..7 hold this lane's 8 d's
    if (myq < LQ) {
        float inv = 1.f / acc[8];
        float* po = out + ooff;
        // regs r=0..3 -> d = 4h+r ; r=4..7 -> d = 8+4h+(r-4)
        float4 r0 = *(float4*)(po + 4 * h);
        r0.x += acc[0] * inv; r0.y += acc[1] * inv;
        r0.z += acc[2] * inv; r0.w += acc[3] * inv;
        *(float4*)(po + 4 * h) = r0;
        float4 r1 = *(float4*)(po + 8 + 4 * h);
        r1.x += acc[4] * inv; r1.y += acc[5] * inv;
        r1.z += acc[6] * inv; r1.w += acc[7] * inv;
        *(float4*)(po + 8 + 4 * h) = r1;
    }
}

extern "C" void kernel_launch(void* const* d_in, const int* in_sizes, int n_in,
                              void* d_out, int out_size, void* d_ws, size_t ws_size,
                              hipStream_t stream) {
    const float* q = (const float*)d_in[0];
    const float* k = (const float*)d_in[1];
    const float* v = (const float*)d_in[2];
    const float* w = (const float*)d_in[3];
    float* out = (float*)d_out;

    rpe_kernel<<<NB_RPE, 256, 0, stream>>>(v, w, out);

    attn_fused<<<NINST * BPI, 320, 0, stream>>>(q, k, v, out);
}

// Round 11
// 37.709 us; speedup vs baseline: 1.3766x; 1.1883x over previous
//
#include <hip/hip_runtime.h>

typedef __bf16 bf16x8 __attribute__((ext_vector_type(8)));
typedef float f32x16 __attribute__((ext_vector_type(16)));
typedef unsigned u32x2 __attribute__((ext_vector_type(2)));

#define BB 2
#define HH 56
#define WW 56
#define NN 2
#define CC 128
#define NH 8
#define DD 16
#define WSP 7
#define LQ 784           // tokens per window = 56*7*2
#define KB_TOK 800       // K rows (zero-padded 784..799)
#define VT_STRIDE 808    // V^T token stride (bf16 elems)
#define NKC 25           // K chunks of 32
#define NINST 128        // 16 windows * 8 heads
#define BPI 5            // blocks per instance
#define NWAVE 5          // waves per block (1 Q-tile each)

// LDS layout (bytes): K [800][16] bf16 | V^T [16][808] bf16 | w [9][16] f32 | ones
#define K_OFF 0
#define V_OFF 25600
#define W_OFF 51456
#define ONES_OFF 52032
#define SMEM_BYTES 52064   // <= 53333 -> 3 blocks/CU

// scale * log2(e) so P = exp2(S) directly (no max-tracking; S bounded)
#define QSCALE 0.3606737602222409f

union U2 { __bf16 h[2]; unsigned u; };
union U4 { unsigned u[4]; bf16x8 v; };
union H8 { bf16x8 v; uint4 q; };

static __device__ __forceinline__ float4 f4zero() { float4 r; r.x = r.y = r.z = r.w = 0.f; return r; }
static __device__ __forceinline__ float4 f4add(float4 a, float4 b) {
    float4 r; r.x = a.x + b.x; r.y = a.y + b.y; r.z = a.z + b.z; r.w = a.w + b.w; return r;
}
static __device__ __forceinline__ float4 f4fma(float4 acc, float4 w, float4 s) {
    acc.x += w.x * s.x; acc.y += w.y * s.y; acc.z += w.z * s.z; acc.w += w.w * s.w; return acc;
}

// Single fused kernel: pack K/V to LDS -> per-wave full-row flash attention ->
// epilogue computes depthwise-conv RPE in-register and stores out = rpe + attn.
// Grid 640 = 128 inst * 5 parts, XCD-affine (inst&7 == bid&7). No workspace,
// no out-RMW, no inter-block dependencies.
__global__ __launch_bounds__(320) void attn_fused(const float* __restrict__ q_g,
                                                  const float* __restrict__ k_g,
                                                  const float* __restrict__ v_g,
                                                  const float* __restrict__ conv_w,
                                                  float* __restrict__ out) {
    __shared__ alignas(16) char smem[SMEM_BYTES];
    __bf16* Klds = (__bf16*)(smem + K_OFF);
    __bf16* Vlds = (__bf16*)(smem + V_OFF);
    float*  wlds = (float*)(smem + W_OFF);
    __bf16* onesb = (__bf16*)(smem + ONES_OFF);

    const int bid  = blockIdx.x;
    const int g    = bid >> 3;             // 0..79
    const int inst = (bid & 7) + 8 * (g / BPI);
    const int part = g % BPI;
    const int head = inst & 7;
    const int win  = inst >> 3;
    const int b    = win >> 3, wj = win & 7;
    const int tid  = threadIdx.x;

    // ---- stage conv weights transposed [k][16] + ones buffer ----
    if (tid < 144) {
        int c = tid & 15, k = tid >> 4;
        wlds[k * 16 + c] = conv_w[(head * 16 + c) * 9 + k];
    } else if (tid < 160) {
        onesb[tid - 144] = (__bf16)1.f;
    }

    // ---- pack phase: f32 K/V -> bf16 LDS (fragment layout) ----
    for (int tok = tid; tok < KB_TOK; tok += 320) {
        if (tok < LQ) {
            int pos = tok >> 1, n = tok & 1;
            int y = pos / WSP, xl2 = pos - y * WSP;
            long off = ((long)(((b * HH + y) * WW + wj * WSP + xl2) * NN + n)) * CC + head * DD;

            float kv[16], vv[16];
            *(float4*)&kv[0]  = *(const float4*)(k_g + off);
            *(float4*)&kv[4]  = *(const float4*)(k_g + off + 4);
            *(float4*)&kv[8]  = *(const float4*)(k_g + off + 8);
            *(float4*)&kv[12] = *(const float4*)(k_g + off + 12);
            *(float4*)&vv[0]  = *(const float4*)(v_g + off);
            *(float4*)&vv[4]  = *(const float4*)(v_g + off + 4);
            *(float4*)&vv[8]  = *(const float4*)(v_g + off + 8);
            *(float4*)&vv[12] = *(const float4*)(v_g + off + 12);

            H8 lo, hi;
#pragma unroll
            for (int i = 0; i < 8; ++i) { lo.v[i] = (__bf16)kv[i]; hi.v[i] = (__bf16)kv[8 + i]; }
            *(uint4*)&Klds[tok * 16]     = lo.q;
            *(uint4*)&Klds[tok * 16 + 8] = hi.q;
#pragma unroll
            for (int d = 0; d < 16; ++d)
                Vlds[d * VT_STRIDE + tok] = (__bf16)vv[d];
        } else {
            H8 z; z.q = make_uint4(0, 0, 0, 0);
            *(uint4*)&Klds[tok * 16]     = z.q;
            *(uint4*)&Klds[tok * 16 + 8] = z.q;
#pragma unroll
            for (int d = 0; d < 16; ++d)
                Vlds[d * VT_STRIDE + tok] = (__bf16)0.f;
        }
    }
    __syncthreads();

    // ---- attention phase: one full Q-tile per wave ----
    const int w    = tid >> 6;             // 0..4
    const int lane = tid & 63;
    const int col  = lane & 31;            // query col / key row / V^T row
    const int h    = lane >> 5;
    const int qt   = part * NWAVE + w;     // 0..24
    const int myq  = qt * 32 + col;
    const int sib  = myq ^ 1;

    const int myqc = myq < LQ ? myq : LQ - 1;
    const int pos = myqc >> 1, n = myqc & 1;
    const int y = pos / WSP, xl = pos - y * WSP;
    const long ooff = ((long)(((b * HH + y) * WW + wj * WSP + xl) * NN + n)) * CC + head * DD;

    // Q fragment (B operand): col=query, k = d = 8h..8h+7; scale*log2e folded
    bf16x8 qfv;
    {
        const float* qp = q_g + ooff + 8 * h;
        float qv[8];
        *(float4*)&qv[0] = *(const float4*)qp;
        *(float4*)&qv[4] = *(const float4*)(qp + 4);
        H8 qq;
#pragma unroll
        for (int i = 0; i < 8; ++i) qq.v[i] = (__bf16)(qv[i] * QSCALE);
        qfv = qq.v;
    }

    f32x16 acc, zv;
#pragma unroll
    for (int i = 0; i < 16; ++i) { acc[i] = 0.f; zv[i] = 0.f; }

    const char* kbase = (const char*)Klds + col * 32 + h * 16;       // + c*1024
    // V fragment source: data rows for col<16; stride-0 ones broadcast else
    const char* vbase;
    int vstep, tstep;
    if (col < 16) {
        vbase = (const char*)Vlds + col * (VT_STRIDE * 2) + h * 16;
        vstep = 64; tstep = 32;
    } else {
        vbase = (const char*)onesb;
        vstep = 0; tstep = 0;
    }

    for (int c = 0; c < NKC; ++c) {
        bf16x8 kf = *(const bf16x8*)(kbase + c * 1024);

        f32x16 st = __builtin_amdgcn_mfma_f32_32x32x16_bf16(kf, qfv, zv, 0, 0, 0);

        float p[16];
        if (c == qt || c == NKC - 1) {  // only these chunks need masking
#pragma unroll
            for (int r = 0; r < 16; ++r) {
                int kr = (r & 3) + 8 * (r >> 2) + 4 * h;
                int gk = c * 32 + kr;
                p[r] = (gk >= LQ || gk == sib) ? 0.f : __builtin_amdgcn_exp2f(st[r]);
            }
        } else {
#pragma unroll
            for (int r = 0; r < 16; ++r) p[r] = __builtin_amdgcn_exp2f(st[r]);
        }

        // pack P to bf16 pairs; pk[b2] covers keys 8*b2+4h..+3 of this chunk
        unsigned pk[4][2];
#pragma unroll
        for (int b2 = 0; b2 < 4; ++b2) {
            U2 a, bb;
            a.h[0]  = (__bf16)p[4 * b2 + 0];
            a.h[1]  = (__bf16)p[4 * b2 + 1];
            bb.h[0] = (__bf16)p[4 * b2 + 2];
            bb.h[1] = (__bf16)p[4 * b2 + 3];
            pk[b2][0] = a.u;
            pk[b2][1] = bb.u;
        }

#pragma unroll
        for (int t = 0; t < 2; ++t) {
            U4 pb;
#pragma unroll
            for (int j = 0; j < 2; ++j) {
#if __has_builtin(__builtin_amdgcn_permlane32_swap)
                u32x2 rr = __builtin_amdgcn_permlane32_swap(pk[2 * t][j], pk[2 * t + 1][j], false, false);
                pb.u[j]     = rr[0];
                pb.u[2 + j] = rr[1];
#else
                unsigned swa = __shfl_xor(pk[2 * t][j], 32, 64);
                unsigned swb = __shfl_xor(pk[2 * t + 1][j], 32, 64);
                pb.u[j]     = h ? swb : pk[2 * t][j];
                pb.u[2 + j] = h ? pk[2 * t + 1][j] : swa;
#endif
            }
            bf16x8 vf = *(const bf16x8*)(vbase + c * vstep + t * tstep);
            acc = __builtin_amdgcn_mfma_f32_32x32x16_bf16(vf, pb.v, acc, 0, 0, 0);
        }
    }

    // ---- epilogue: in-register depthwise-conv RPE + write out (no RMW) ----
    // acc[8] = lsum (ones broadcast); regs 0..3 -> d=4h+r, 4..7 -> d=8+4h+(r-4)
    if (myq < LQ) {
        const int xg = wj * WSP + xl;
        const long rowbase = ((long)(b * HH + y) * WW + xg) * (NN * CC) + head * DD;

        float4 cv0 = f4zero(), cv1 = f4zero();
        float4 sc0 = f4zero(), sc1 = f4zero();
        float4 vn0 = f4zero(), vn1 = f4zero();

#pragma unroll
        for (int dy = -1; dy <= 1; ++dy) {
            int yy = y + dy;
#pragma unroll
            for (int dx = -1; dx <= 1; ++dx) {
                int xx = xg + dx;
                if (yy < 0 || yy >= HH || xx < 0 || xx >= WW) continue;
                int k = (dy + 1) * 3 + (dx + 1);
                const float* p = v_g + rowbase + ((long)dy * WW + dx) * (NN * CC);
                float4 a0 = *(const float4*)(p + 4 * h);
                float4 b0 = *(const float4*)(p + CC + 4 * h);
                float4 a1 = *(const float4*)(p + 8 + 4 * h);
                float4 b1 = *(const float4*)(p + CC + 8 + 4 * h);
                float4 w0 = *(const float4*)(wlds + k * 16 + 4 * h);
                float4 w1 = *(const float4*)(wlds + k * 16 + 8 + 4 * h);
                float4 S0 = f4add(a0, b0);
                float4 S1 = f4add(a1, b1);
                cv0 = f4fma(cv0, w0, S0);
                cv1 = f4fma(cv1, w1, S1);
                if (dy == 0 && dx == 0) {
                    sc0 = S0; sc1 = S1;
                    vn0 = n ? b0 : a0;
                    vn1 = n ? b1 : a1;
                }
            }
        }
        float4 wc0 = *(const float4*)(wlds + 4 * 16 + 4 * h);
        float4 wc1 = *(const float4*)(wlds + 4 * 16 + 8 + 4 * h);

        float inv = 1.f / acc[8];
        float* po = out + ooff;
        float4 r0, r1;
        r0.x = cv0.x + wc0.x * (vn0.x - sc0.x) + acc[0] * inv;
        r0.y = cv0.y + wc0.y * (vn0.y - sc0.y) + acc[1] * inv;
        r0.z = cv0.z + wc0.z * (vn0.z - sc0.z) + acc[2] * inv;
        r0.w = cv0.w + wc0.w * (vn0.w - sc0.w) + acc[3] * inv;
        r1.x = cv1.x + wc1.x * (vn1.x - sc1.x) + acc[4] * inv;
        r1.y = cv1.y + wc1.y * (vn1.y - sc1.y) + acc[5] * inv;
        r1.z = cv1.z + wc1.z * (vn1.z - sc1.z) + acc[6] * inv;
        r1.w = cv1.w + wc1.w * (vn1.w - sc1.w) + acc[7] * inv;
        *(float4*)(po + 4 * h) = r0;
        *(float4*)(po + 8 + 4 * h) = r1;
    }
}

extern "C" void kernel_launch(void* const* d_in, const int* in_sizes, int n_in,
                              void* d_out, int out_size, void* d_ws, size_t ws_size,
                              hipStream_t stream) {
    const float* q = (const float*)d_in[0];
    const float* k = (const float*)d_in[1];
    const float* v = (const float*)d_in[2];
    const float* w = (const float*)d_in[3];
    float* out = (float*)d_out;

    attn_fused<<<NINST * BPI, 320, 0, stream>>>(q, k, v, w, out);
}